// Round 11
// baseline (2258.163 us; speedup 1.0000x reference)
//
#include <hip/hip_runtime.h>
#include <cfloat>
#include <climits>

#define NEG 0.2f
#define GEPS 1e-5f
#define D 6
#define H 13   // 2*D+1
#define KOUT 16

#define GMAX 36
#define MAXC 46656      // GMAX^3
#define MAXPC 16        // atom slots per cell (rest -> spill list)
#define CS_TGT 2.2f     // target cell size
#define CAPG 256        // survivor slots per query
#define WPB 4           // waves (queries) per block

__device__ __forceinline__ float lrelu(float x){ return x >= 0.f ? x : NEG*x; }

// order-preserving float<->uint for atomic min/max
__device__ __forceinline__ unsigned fkey(float f){
  unsigned u = __float_as_uint(f);
  return (u & 0x80000000u) ? ~u : (u | 0x80000000u);
}
__device__ __forceinline__ float funkey(unsigned u){
  return __uint_as_float((u & 0x80000000u) ? (u ^ 0x80000000u) : ~u);
}

struct GridP {
  float bx,by,bz, csx,csy,csz, ivx,ivy,ivz;
  int gx,gy,gz;
};
// identical fp path in every kernel -> identical grid params
__device__ __forceinline__ GridP load_grid(const unsigned* bb){
  GridP g;
  g.bx = funkey(bb[0]); g.by = funkey(bb[1]); g.bz = funkey(bb[2]);
  float sx = fmaxf(funkey(bb[3]) - g.bx, 1e-5f);
  float sy = fmaxf(funkey(bb[4]) - g.by, 1e-5f);
  float sz = fmaxf(funkey(bb[5]) - g.bz, 1e-5f);
  int gx = (int)(sx/CS_TGT) + 1; gx = gx < 1 ? 1 : (gx > GMAX ? GMAX : gx);
  int gy = (int)(sy/CS_TGT) + 1; gy = gy < 1 ? 1 : (gy > GMAX ? GMAX : gy);
  int gz = (int)(sz/CS_TGT) + 1; gz = gz < 1 ? 1 : (gz > GMAX ? GMAX : gz);
  g.gx = gx; g.gy = gy; g.gz = gz;
  g.csx = sx/gx; g.csy = sy/gy; g.csz = sz/gz;
  g.ivx = gx/sx; g.ivy = gy/sy; g.ivz = gz/sz;
  return g;
}
__device__ __forceinline__ int cell1(float x, float b, float iv, int gdim){
  int c = (int)((x - b)*iv);
  return c < 0 ? 0 : (c >= gdim ? gdim-1 : c);
}

// ---------------- build kernels ----------------
__global__ void init_kernel(unsigned* bb, unsigned* fill, unsigned* spillCnt){
  int i = blockIdx.x*blockDim.x + threadIdx.x;
  if (i < MAXC) fill[i] = 0;
  if (i == 0){
    bb[0]=bb[1]=bb[2]=0xFFFFFFFFu;
    bb[3]=bb[4]=bb[5]=0u;
    spillCnt[0]=0;
  }
}

__global__ void bbox_kernel(const float* __restrict__ xyz, int n, unsigned* bb){
  int i = blockIdx.x*blockDim.x + threadIdx.x;
  if (i >= n) return;
  float x = xyz[3*i], y = xyz[3*i+1], z = xyz[3*i+2];
  atomicMin(&bb[0], fkey(x)); atomicMin(&bb[1], fkey(y)); atomicMin(&bb[2], fkey(z));
  atomicMax(&bb[3], fkey(x)); atomicMax(&bb[4], fkey(y)); atomicMax(&bb[5], fkey(z));
}

__global__ void scatter_kernel(const float* __restrict__ xyz, int n,
                               const unsigned* __restrict__ bb,
                               unsigned* fill, ushort* cellIdx,
                               ushort* spill, unsigned* spillCnt){
  int i = blockIdx.x*blockDim.x + threadIdx.x;
  if (i >= n) return;
  GridP g = load_grid(bb);
  float x = xyz[3*i], y = xyz[3*i+1], z = xyz[3*i+2];
  int cx = cell1(x, g.bx, g.ivx, g.gx);
  int cy = cell1(y, g.by, g.ivy, g.gy);
  int cz = cell1(z, g.bz, g.ivz, g.gz);
  int cid = (cz*g.gy + cy)*g.gx + cx;
  unsigned pos = atomicAdd(&fill[cid], 1u);
  if (pos < MAXPC) cellIdx[cid*MAXPC + pos] = (ushort)i;
  else {
    unsigned sp = atomicAdd(spillCnt, 1u);
    spill[sp] = (ushort)i;
  }
}

// xyz (n,3) -> float4 {x,y,z,|p|^2} (contract-off to match reference)
__global__ void pack_kernel(const float* __restrict__ xyz, float4* __restrict__ out, int n){
  int i = blockIdx.x*blockDim.x + threadIdx.x;
  if (i >= n) return;
  float x = xyz[3*i], y = xyz[3*i+1], z = xyz[3*i+2];
  float sq;
  {
#pragma clang fp contract(off)
    sq = (x*x + y*y) + z*z;
  }
  out[i] = make_float4(x,y,z,sq);
}

// atomtypes (n,6) -> 2-layer MLP -> out (n,6)
__global__ void tt_kernel(const float* __restrict__ at_in,
                          const float* __restrict__ w1, const float* __restrict__ b1,
                          const float* __restrict__ w2, const float* __restrict__ b2,
                          float* __restrict__ out, int n){
  int i = blockIdx.x*blockDim.x + threadIdx.x;
  if (i >= n) return;
  float x[D], h[D];
  #pragma unroll
  for (int j=0;j<D;j++) x[j] = at_in[i*D+j];
  #pragma unroll
  for (int o=0;o<D;o++){
    float acc = b1[o];
    #pragma unroll
    for (int j=0;j<D;j++) acc += w1[o*D+j]*x[j];
    h[o] = lrelu(acc);
  }
  #pragma unroll
  for (int o=0;o<D;o++){
    float acc = b2[o];
    #pragma unroll
    for (int j=0;j<D;j++) acc += w2[o*D+j]*h[j];
    out[i*D+o] = acc;
  }
}

// ascending value bitonic sort across 64 lanes
__device__ __forceinline__ void sort64f1(float& a, int lane){
  #pragma unroll
  for (int k=2;k<=64;k<<=1){
    #pragma unroll
    for (int j=k>>1;j>=1;j>>=1){
      float o = __shfl_xor(a, j);
      bool dir = ((lane&j)==0)==((lane&k)==0);
      a = dir ? fminf(a,o) : fmaxf(a,o);
    }
  }
}

// ascending lexicographic (d, i) bitonic sort across 64 lanes
__device__ __forceinline__ void sort64pair(float& d, int& i, int lane){
  #pragma unroll
  for (int k = 2; k <= 64; k <<= 1){
    #pragma unroll
    for (int j = k >> 1; j >= 1; j >>= 1){
      float od = __shfl_xor(d, j);
      int   oi = __shfl_xor(i, j);
      bool lower = (lane & j) == 0;
      bool asc   = (lane & k) == 0;
      bool oless = (od < d) || (od == d && oi < i);
      bool take  = (lower == asc) ? oless : !oless;
      d = take ? od : d;
      i = take ? oi : i;
    }
  }
}

// Grid KNN: one wave per query; expanding Chebyshev shells of cells.
// Exact: selection metric is the reference contract-off d2 computed per
// candidate at insertion; pruning/stop use a provable UPPER bound on the true
// k-th (17th smallest of per-lane inserted minima = 17 distinct witnesses),
// so top-KSEL is always within the inserted set; final exact lex sort emits.
template<int KSEL, int OUT_OFF>
__global__ __launch_bounds__(256)
void knn_grid_kernel(const float4* __restrict__ candP, int ncand,
                     const float4* __restrict__ qarr, int nq,
                     const unsigned* __restrict__ bb,
                     const unsigned* __restrict__ fill,
                     const ushort* __restrict__ cellIdx,
                     const ushort* __restrict__ spill,
                     const unsigned* __restrict__ spillCnt,
                     int* __restrict__ oidx, float* __restrict__ odist){
  __shared__ float sd[WPB][CAPG];
  __shared__ int   si[WPB][CAPG];
  __shared__ int   scnt[WPB];

  const int w = threadIdx.x >> 6;
  const int lane = threadIdx.x & 63;
  const int q = blockIdx.x*WPB + w;
  if (q >= nq) return;                     // wave-uniform; no barriers used

  if (lane == 0) scnt[w] = 0;
  __threadfence_block();

  const GridP g = load_grid(bb);
  const float4 qv = qarr[q];
  const int c0x = cell1(qv.x, g.bx, g.ivx, g.gx);
  const int c0y = cell1(qv.y, g.by, g.ivy, g.gy);
  const int c0z = cell1(qv.z, g.bz, g.ivz, g.gz);

  float upper = FLT_MAX; bool hasup = false;
  float lmin = FLT_MAX;                    // min d2 this lane inserted
  const int spc = (int)spillCnt[0];

  for (int s = 0; s <= GMAX; ++s){
    const int B = 2*s+1, B2 = B*B, nbox = B2*B;
    const float rB2 = 1.0f/(float)B2, rB = 1.0f/(float)B;
    for (int t = lane; t < nbox; t += 64){
      int dz = (int)(((float)t + 0.5f)*rB2);
      int r2 = t - dz*B2;
      int dy = (int)(((float)r2 + 0.5f)*rB);
      int dx = r2 - dy*B;
      dx -= s; dy -= s; dz -= s;
      int ax = dx<0?-dx:dx, ay = dy<0?-dy:dy, az = dz<0?-dz:dz;
      int ch = ax>ay?ax:ay; ch = ch>az?ch:az;
      if (ch != s) continue;               // interior done in earlier shells
      int cx = c0x+dx, cy = c0y+dy, cz = c0z+dz;
      if (cx<0 || cx>=g.gx || cy<0 || cy>=g.gy || cz<0 || cz>=g.gz) continue;
      int cid = (cz*g.gy + cy)*g.gx + cx;
      int nc = (int)fill[cid];
      int nreal = nc > MAXPC ? MAXPC : nc;
      if (nreal == 0) continue;
      if (hasup){
        float lox = g.bx + cx*g.csx, loy = g.by + cy*g.csy, loz = g.bz + cz*g.csz;
        float dxx = fmaxf(fmaxf(lox - qv.x, qv.x - (lox + g.csx)), 0.f);
        float dyy = fmaxf(fmaxf(loy - qv.y, qv.y - (loy + g.csy)), 0.f);
        float dzz = fmaxf(fmaxf(loz - qv.z, qv.z - (loz + g.csz)), 0.f);
        float lb = dxx*dxx + dyy*dyy + dzz*dzz;
        if (lb > upper + 0.01f) continue;  // margin covers fp in lb/d2
      }
      for (int a = 0; a < nreal; ++a){
        int gi = (int)cellIdx[cid*MAXPC + a];
        float4 cp = candP[gi];
        float d2;
        {
#pragma clang fp contract(off)
          float dot = qv.x*cp.x + qv.y*cp.y + qv.z*cp.z;
          d2 = (qv.w + cp.w) - 2.0f*dot;
        }
        if (d2 <= upper){                  // upper==FLT_MAX before valid
          int ofs = atomicAdd(&scnt[w], 1);
          if (ofs < CAPG){ sd[w][ofs] = d2; si[w][ofs] = gi; }
          lmin = fminf(lmin, d2);
        }
      }
    }
    if (s == 0 && spc > 0){                // cell-overflow spill (usually 0)
      for (int t = lane; t < spc; t += 64){
        int gi = (int)spill[t];
        float4 cp = candP[gi];
        float d2;
        {
#pragma clang fp contract(off)
          float dot = qv.x*cp.x + qv.y*cp.y + qv.z*cp.z;
          d2 = (qv.w + cp.w) - 2.0f*dot;
        }
        if (d2 <= upper){
          int ofs = atomicAdd(&scnt[w], 1);
          if (ofs < CAPG){ sd[w][ofs] = d2; si[w][ofs] = gi; }
          lmin = fminf(lmin, d2);
        }
      }
    }
    // refresh upper bound: KSEL-th smallest of per-lane inserted minima
    unsigned long long bal = __ballot(lmin < FLT_MAX);
    if (__popcll(bal) >= KSEL){
      float v = lmin;
      sort64f1(v, lane);
      upper = __shfl(v, KSEL-1);
      hasup = true;
    }
    // full-coverage break
    bool cov = (c0x-s <= 0) && (c0x+s >= g.gx-1) &&
               (c0y-s <= 0) && (c0y+s >= g.gy-1) &&
               (c0z-s <= 0) && (c0z+s >= g.gz-1);
    if (cov) break;
    // distance-bound break: everything outside B_s is provably > upper
    if (hasup){
      float m = fminf(qv.x - (g.bx + (c0x-s)*g.csx), (g.bx + (c0x+s+1)*g.csx) - qv.x);
      m = fminf(m, fminf(qv.y - (g.by + (c0y-s)*g.csy), (g.by + (c0y+s+1)*g.csy) - qv.y));
      m = fminf(m, fminf(qv.z - (g.bz + (c0z-s)*g.csz), (g.bz + (c0z+s+1)*g.csz) - qv.z));
      float mm = m - 0.01f;
      if (mm > 0.f && upper <= mm*mm) break;
    }
  }

  __threadfence_block();
  const int C = scnt[w];

  bool ok64 = false; int Cs = 0;
  float dd = FLT_MAX; int gg = INT_MAX;
  if (C <= 64){
    if (lane < C){ dd = sd[w][lane]; gg = si[w][lane]; }
    ok64 = true; Cs = C;
  } else if (C <= CAPG && hasup){
    // compact survivors (d2 <= upper ⊇ exact top-KSEL) to <= 64
    float ed[4]; int ei[4];
    #pragma unroll
    for (int u=0;u<4;++u){
      int p = lane + 64*u;
      bool v = p < C;
      ed[u] = v ? sd[w][p] : FLT_MAX;
      ei[u] = v ? si[w][p] : INT_MAX;
    }
    __threadfence_block();
    int base = 0;
    const unsigned long long ltm = (1ULL<<lane) - 1ULL;
    #pragma unroll
    for (int u=0;u<4;++u){
      bool keep = (ed[u] <= upper);
      unsigned long long m = __ballot(keep);
      if (keep){
        int o = base + __popcll(m & ltm);
        if (o < 64){ sd[w][o] = ed[u]; si[w][o] = ei[u]; }
      }
      base += __popcll(m);
    }
    __threadfence_block();
    if (base <= 64){
      if (lane < base){ dd = sd[w][lane]; gg = si[w][lane]; }
      ok64 = true; Cs = base;
    }
  }

  if (ok64 && Cs >= KSEL){
    sort64pair(dd, gg, lane);
    if (lane >= OUT_OFF && lane < OUT_OFF + KOUT){
      float4 cp = candP[gg];
      float dist;
      {
#pragma clang fp contract(off)
        float dx = qv.x-cp.x, dy = qv.y-cp.y, dz = qv.z-cp.z;
        dist = (dx*dx + dy*dy) + dz*dz;
      }
      oidx[(size_t)q*KOUT + (lane-OUT_OFF)]  = gg;
      odist[(size_t)q*KOUT + (lane-OUT_OFF)] = dist;
    }
  } else if (lane == 0){
    // rare fallback: serial exact full scan (proven R9 path)
    float bd[KSEL]; int bi[KSEL];
    #pragma unroll
    for (int t=0;t<KSEL;t++){ bd[t]=FLT_MAX; bi[t]=INT_MAX; }
    float cmd = FLT_MAX; int cmi = INT_MAX;
    for (int jj = 0; jj < ncand; ++jj){
      float4 cp = candP[jj];
      float d2;
      {
#pragma clang fp contract(off)
        float dot = qv.x*cp.x + qv.y*cp.y + qv.z*cp.z;
        d2 = (qv.w + cp.w) - 2.0f*dot;
      }
      if (d2 < cmd || (d2 == cmd && jj < cmi)){
        int rt = 0; float rmd=-FLT_MAX; int rmi=-1;
        for (int t=0;t<KSEL;t++){
          if (bd[t] > rmd || (bd[t]==rmd && bi[t]>rmi)){ rmd=bd[t]; rmi=bi[t]; rt=t; }
        }
        bd[rt]=d2; bi[rt]=jj;
        cmd=-FLT_MAX; cmi=-1;
        for (int t=0;t<KSEL;t++){
          if (bd[t] > cmd || (bd[t]==cmd && bi[t]>cmi)){ cmd=bd[t]; cmi=bi[t]; }
        }
      }
    }
    for (int t=0;t<KSEL;t++){
      int rt=-1; float mnd=FLT_MAX; int mni=INT_MAX;
      for (int u2=0;u2<KSEL;u2++){
        if (bd[u2] < mnd || (bd[u2]==mnd && bi[u2]<mni)){ mnd=bd[u2]; mni=bi[u2]; rt=u2; }
      }
      bd[rt]=FLT_MAX; bi[rt]=INT_MAX;
      if (t >= OUT_OFF){
        float4 cp = candP[mni];
        float dist;
        {
#pragma clang fp contract(off)
          float dx=qv.x-cp.x, dy=qv.y-cp.y, dz=qv.z-cp.z;
          dist = (dx*dx + dy*dy) + dz*dz;
        }
        oidx[(size_t)q*KOUT + (t-OUT_OFF)]  = mni;
        odist[(size_t)q*KOUT + (t-OUT_OFF)] = dist;
      }
    }
  }
}

// One message-passing block: out = self + lrelu(groupnorm(sum_k MLP(feat_k)))
// 4 threads per point: each handles 4 of the 16 neighbors, shfl-reduce.
template<bool SELF_ONES>
__global__ __launch_bounds__(256)
void mp_kernel(const float* __restrict__ self_feat,
               const float* __restrict__ nb_src,
               const int* __restrict__ idx,
               const float* __restrict__ dists,
               const float* __restrict__ w1g, const float* __restrict__ b1g,
               const float* __restrict__ w2g, const float* __restrict__ b2g,
               const float* __restrict__ gam, const float* __restrict__ bet,
               float* __restrict__ out, int n){
  __shared__ float w1[H*H], b1v[H], w2[D*H], b2v[D], gm[D], bt[D];
  for (int t=threadIdx.x; t<H*H; t+=blockDim.x) w1[t]=w1g[t];
  if (threadIdx.x < H) b1v[threadIdx.x]=b1g[threadIdx.x];
  for (int t=threadIdx.x; t<D*H; t+=blockDim.x) w2[t]=w2g[t];
  if (threadIdx.x < D){
    b2v[threadIdx.x]=b2g[threadIdx.x];
    gm[threadIdx.x]=gam[threadIdx.x];
    bt[threadIdx.x]=bet[threadIdx.x];
  }
  __syncthreads();
  int tt = blockIdx.x*blockDim.x + threadIdx.x;
  int p = tt >> 2, sub = tt & 3;
  if (p >= n) return;

  float s[D];
  #pragma unroll
  for (int j=0;j<D;j++) s[j] = SELF_ONES ? 1.0f : self_feat[p*D+j];
  float msg[D] = {0,0,0,0,0,0};

  #pragma unroll
  for (int u=0;u<KOUT/4;u++){
    int k = u*4 + sub;
    int j = idx[p*KOUT+k];
    float dd = dists[p*KOUT+k];
    float f[H];
    #pragma unroll
    for (int c=0;c<D;c++) f[c]=s[c];
    #pragma unroll
    for (int c=0;c<D;c++) f[D+c]=nb_src[j*D+c];
    f[2*D]=dd;
    float h[H];
    #pragma unroll
    for (int o=0;o<H;o++){
      float acc=b1v[o];
      #pragma unroll
      for (int c=0;c<H;c++) acc += w1[o*H+c]*f[c];
      h[o]=lrelu(acc);
    }
    #pragma unroll
    for (int o=0;o<D;o++){
      float acc=b2v[o];
      #pragma unroll
      for (int c=0;c<H;c++) acc += w2[o*H+c]*h[c];
      msg[o]+=acc;
    }
  }

  #pragma unroll
  for (int c=0;c<D;c++){
    msg[c] += __shfl_xor(msg[c], 1);
    msg[c] += __shfl_xor(msg[c], 2);
  }

  if (sub == 0){
    float y[D];
    #pragma unroll
    for (int gi=0; gi<2; gi++){
      float m0=msg[gi*3+0], m1=msg[gi*3+1], m2=msg[gi*3+2];
      float mu = ((m0+m1)+m2) / 3.0f;
      float d0=m0-mu, d1=m1-mu, d2v=m2-mu;
      float var = ((d0*d0 + d1*d1) + d2v*d2v) / 3.0f;
      float inv = 1.0f / sqrtf(var + GEPS);
      y[gi*3+0] = d0*inv;
      y[gi*3+1] = d1*inv;
      y[gi*3+2] = d2v*inv;
    }
    #pragma unroll
    for (int c=0;c<D;c++){
      float vv = y[c]*gm[c] + bt[c];
      out[p*D+c] = s[c] + lrelu(vv);
    }
  }
}

extern "C" void kernel_launch(void* const* d_in, const int* in_sizes, int n_in,
                              void* d_out, int out_size, void* d_ws, size_t ws_size,
                              hipStream_t stream){
  const float* xyz       = (const float*)d_in[0];
  const float* atom_xyz  = (const float*)d_in[1];
  const float* atomtypes = (const float*)d_in[2];
  const float* tt_w1 = (const float*)d_in[5];
  const float* tt_b1 = (const float*)d_in[6];
  const float* tt_w2 = (const float*)d_in[7];
  const float* tt_b2 = (const float*)d_in[8];
  const float* aa_w1 = (const float*)d_in[9];
  const float* aa_b1 = (const float*)d_in[10];
  const float* aa_w2 = (const float*)d_in[11];
  const float* aa_b2 = (const float*)d_in[12];
  const float* aa_gamma = (const float*)d_in[13];
  const float* aa_beta  = (const float*)d_in[14];
  const float* em_w1 = (const float*)d_in[15];
  const float* em_b1 = (const float*)d_in[16];
  const float* em_w2 = (const float*)d_in[17];
  const float* em_b2 = (const float*)d_in[18];
  const float* em_gamma = (const float*)d_in[19];
  const float* em_beta  = (const float*)d_in[20];

  const int n_pts = in_sizes[0]/3;
  const int n_at  = in_sizes[1]/3;

  char* ws = (char*)d_ws;
  float4* candP = (float4*)ws; ws += (size_t)n_at*sizeof(float4);
  float4* ptsP  = (float4*)ws; ws += (size_t)n_pts*sizeof(float4);
  float* fa   = (float*)ws; ws += (size_t)n_at*D*4;
  float* fb   = (float*)ws; ws += (size_t)n_at*D*4;
  int*   idxA = (int*)ws;   ws += (size_t)n_at*KOUT*4;
  float* distA= (float*)ws; ws += (size_t)n_at*KOUT*4;
  int*   idxP = (int*)ws;   ws += (size_t)n_pts*KOUT*4;
  float* distP= (float*)ws; ws += (size_t)n_pts*KOUT*4;
  float* ea   = (float*)ws; ws += (size_t)n_pts*D*4;
  float* eb   = (float*)ws; ws += (size_t)n_pts*D*4;
  unsigned* bbx   = (unsigned*)ws; ws += 8*4;
  unsigned* spCnt = (unsigned*)ws; ws += 8*4;
  unsigned* fill  = (unsigned*)ws; ws += (size_t)MAXC*4;
  ushort* cellIdx = (ushort*)ws;   ws += (size_t)MAXC*MAXPC*2;
  ushort* spill   = (ushort*)ws;   ws += (size_t)8192*2;
  float* outf = (float*)d_out;

  // ---- grid build ----
  init_kernel<<<(MAXC+255)/256,256,0,stream>>>(bbx, fill, spCnt);
  bbox_kernel<<<(n_at+255)/256,256,0,stream>>>(atom_xyz, n_at, bbx);
  scatter_kernel<<<(n_at+255)/256,256,0,stream>>>(atom_xyz, n_at, bbx, fill, cellIdx, spill, spCnt);

  pack_kernel<<<(n_at +255)/256,256,0,stream>>>(atom_xyz, candP, n_at);
  pack_kernel<<<(n_pts+255)/256,256,0,stream>>>(xyz, ptsP, n_pts);

  tt_kernel<<<(n_at+255)/256,256,0,stream>>>(atomtypes, tt_w1,tt_b1,tt_w2,tt_b2, fa, n_at);

  // ---- atom-atom KNN (k=17, drop self) ----
  knn_grid_kernel<17,1><<<(n_at+WPB-1)/WPB,256,0,stream>>>(
      candP, n_at, candP, n_at, bbx, fill, cellIdx, spill, spCnt, idxA, distA);

  mp_kernel<false><<<(n_at*4+255)/256,256,0,stream>>>(fa, fa, idxA, distA,
      aa_w1+0*H*H, aa_b1+0*H, aa_w2+0*D*H, aa_b2+0*D, aa_gamma+0*D, aa_beta+0*D, fb, n_at);
  mp_kernel<false><<<(n_at*4+255)/256,256,0,stream>>>(fb, fb, idxA, distA,
      aa_w1+1*H*H, aa_b1+1*H, aa_w2+1*D*H, aa_b2+1*D, aa_gamma+1*D, aa_beta+1*D, fa, n_at);
  mp_kernel<false><<<(n_at*4+255)/256,256,0,stream>>>(fa, fa, idxA, distA,
      aa_w1+2*H*H, aa_b1+2*H, aa_w2+2*D*H, aa_b2+2*D, aa_gamma+2*D, aa_beta+2*D, fb, n_at);
  // final atom features in fb

  // ---- point-atom KNN (k=16) ----
  knn_grid_kernel<16,0><<<(n_pts+WPB-1)/WPB,256,0,stream>>>(
      candP, n_at, ptsP, n_pts, bbx, fill, cellIdx, spill, spCnt, idxP, distP);

  mp_kernel<true ><<<(n_pts*4+255)/256,256,0,stream>>>(nullptr, fb, idxP, distP,
      em_w1+0*H*H, em_b1+0*H, em_w2+0*D*H, em_b2+0*D, em_gamma+0*D, em_beta+0*D, ea, n_pts);
  mp_kernel<false><<<(n_pts*4+255)/256,256,0,stream>>>(ea, fb, idxP, distP,
      em_w1+1*H*H, em_b1+1*H, em_w2+1*D*H, em_b2+1*D, em_gamma+1*D, em_beta+1*D, eb, n_pts);
  mp_kernel<false><<<(n_pts*4+255)/256,256,0,stream>>>(eb, fb, idxP, distP,
      em_w1+2*H*H, em_b1+2*H, em_w2+2*D*H, em_b2+2*D, em_gamma+2*D, em_beta+2*D, outf, n_pts);
}